// Round 1
// 293.044 us; speedup vs baseline: 1.0119x; 1.0119x over previous
//
#include <hip/hip_runtime.h>
#include <hip/hip_bf16.h>

// GAT 2-layer forward. N=50000, E=800000 (+N self loops), IN=256,
// layer1: 8 heads x 32 (concat -> 256), relu, layer2: 256 -> 64, 1 head.
// Round 12: edge-slot-parallel gathers. gather1: wave = 4 nodes x 4 edge
// slots x 4 channel lanes (16 edges/node/round, shfl_xor(4,8) reduce) —
// cuts serial gather rounds ~7 -> ~2 and quadruples wave count.
// gather2: wave = 1 node x 4 slots x 16 ch-lanes, shfl_xor(16,32) reduce.

#define HEADS 8
#define HID 32
#define F1 256   // IN and layer-1 output width (8*32)
#define F2 64    // layer-2 output width
#define NEG_SLOPE 0.2f
#define CAP 128  // bucket slots per node (max in-degree ~45 for Poisson(16))

typedef __attribute__((ext_vector_type(8))) short bf16x8;
typedef __attribute__((ext_vector_type(4))) float f32x4;
typedef __attribute__((ext_vector_type(8))) unsigned short u16x8;

__device__ __forceinline__ unsigned short f2b(float f) {
    union { float f; unsigned int i; } x; x.f = f;
    unsigned int r = x.i + 0x7fffu + ((x.i >> 16) & 1u);  // RNE
    return (unsigned short)(r >> 16);
}
__device__ __forceinline__ float b2f(unsigned short u) {
    union { unsigned int i; float f; } x; x.i = ((unsigned int)u) << 16;
    return x.f;
}
__device__ __forceinline__ float leaky(float v) {
    return v > 0.f ? v : NEG_SLOPE * v;
}

// ---------------- setup: W1T, W2T casts + cursor zero -------------------
__global__ void setup_kernel(const float* __restrict__ W1,
                             const float* __restrict__ W2,
                             unsigned short* __restrict__ W1T,
                             unsigned short* __restrict__ W2T,
                             int* __restrict__ cursor, int Nn) {
    const int i = blockIdx.x * 256 + threadIdx.x;
    if (i < F1 * F1) {                       // W1 [F1,F1] -> W1T [n][k]
        const int k = i >> 8, n = i & (F1 - 1);
        W1T[(size_t)n * F1 + k] = f2b(W1[i]);
    } else if (i < F1 * F1 + F1 * F2) {      // W2 [F1,F2] -> W2T [n][k]
        const int j = i - F1 * F1;
        const int k = j >> 6, n = j & (F2 - 1);
        W2T[(size_t)n * F1 + k] = f2b(W2[j]);
    } else if (i < F1 * F1 + F1 * F2 + Nn) {
        cursor[i - F1 * F1 - F1 * F2] = 0;
    }
}

// ---------------- bucket scatter (by dst) -------------------------------
__global__ void scatter_kernel(const int* __restrict__ ei, int E,
                               int* __restrict__ cursor,
                               int* __restrict__ bucket) {
    const int e = blockIdx.x * blockDim.x + threadIdx.x;
    if (e >= E) return;
    const int d = ei[E + e];
    const int pos = atomicAdd(&cursor[d], 1);
    if (pos < CAP) bucket[(size_t)d * CAP + pos] = ei[e];
}

// ---------------- MFMA GEMM: C[M,N] = A[M,K] @ BT[N,K]^T ----------------
// OUT_MODE: 0 = fp32 node-major, 1 = bf16 node-major,
//           2 = bf16 head-major [col/32][row][32]
template<int BN, bool A_FP32, int OUT_MODE>
__global__ __launch_bounds__(256) void mfma_gemm(
        const void* __restrict__ A,
        const unsigned short* __restrict__ BT,
        void* __restrict__ C, int M, int N, int K) {
    constexpr int BM = 128, BK = 32;
    __shared__ unsigned short As[BM * BK];
    __shared__ unsigned short Bs[BN * BK];
    const int tid = threadIdx.x;
    const int wave = tid >> 6, lane = tid & 63;
    const int quad = lane >> 4, l16 = lane & 15;
    const int brow = blockIdx.x * BM;
    const int bcol = blockIdx.y * BN;

    constexpr int MI = (BN == 128) ? 4 : 2;
    constexpr int NJ = 4;
    const int wm = (BN == 128) ? (wave & 1) * 64 : wave * 32;
    const int wn = (BN == 128) ? (wave >> 1) * 64 : 0;

    f32x4 acc[MI][NJ] = {};

    for (int k0 = 0; k0 < K; k0 += BK) {
#pragma unroll
        for (int it = 0; it < (BM * BK) / (256 * 8); ++it) {
            const int idx = it * 256 + tid;
            const int r = idx >> 2;
            const int kk = (idx & 3) * 8;
            const int gr = brow + r;
            if (A_FP32) {
                const float* Af = (const float*)A;
                float4 a0 = make_float4(0.f, 0.f, 0.f, 0.f);
                float4 a1 = make_float4(0.f, 0.f, 0.f, 0.f);
                if (gr < M) {
                    a0 = *(const float4*)&Af[(size_t)gr * K + k0 + kk];
                    a1 = *(const float4*)&Af[(size_t)gr * K + k0 + kk + 4];
                }
                ushort4 lo, hi;
                lo.x = f2b(a0.x); lo.y = f2b(a0.y); lo.z = f2b(a0.z); lo.w = f2b(a0.w);
                hi.x = f2b(a1.x); hi.y = f2b(a1.y); hi.z = f2b(a1.z); hi.w = f2b(a1.w);
                *(ushort4*)&As[r * BK + kk] = lo;
                *(ushort4*)&As[r * BK + kk + 4] = hi;
            } else {
                const unsigned short* Ab = (const unsigned short*)A;
                uint4 v = make_uint4(0u, 0u, 0u, 0u);
                if (gr < M) v = *(const uint4*)&Ab[(size_t)gr * K + k0 + kk];
                *(uint4*)&As[r * BK + kk] = v;
            }
        }
#pragma unroll
        for (int it = 0; it < (BN * BK) / (256 * 8); ++it) {
            const int idx = it * 256 + tid;
            const int r = idx >> 2;
            const int kk = (idx & 3) * 8;
            const uint4 v = *(const uint4*)&BT[(size_t)(bcol + r) * K + k0 + kk];
            *(uint4*)&Bs[r * BK + kk] = v;
        }
        __syncthreads();
        bf16x8 af[MI], bfr[NJ];
#pragma unroll
        for (int i = 0; i < MI; ++i)
            af[i] = *(const bf16x8*)&As[(wm + i * 16 + l16) * BK + quad * 8];
#pragma unroll
        for (int j = 0; j < NJ; ++j)
            bfr[j] = *(const bf16x8*)&Bs[(wn + j * 16 + l16) * BK + quad * 8];
#pragma unroll
        for (int i = 0; i < MI; ++i)
#pragma unroll
            for (int j = 0; j < NJ; ++j)
                acc[i][j] = __builtin_amdgcn_mfma_f32_16x16x32_bf16(
                    af[i], bfr[j], acc[i][j], 0, 0, 0);
        __syncthreads();
    }
#pragma unroll
    for (int i = 0; i < MI; ++i) {
#pragma unroll
        for (int r = 0; r < 4; ++r) {
            const int row = brow + wm + i * 16 + quad * 4 + r;
            if (row >= M) continue;
#pragma unroll
            for (int j = 0; j < NJ; ++j) {
                const int col = bcol + wn + j * 16 + l16;
                const float v = acc[i][j][r];
                if (OUT_MODE == 0) {
                    ((float*)C)[(size_t)row * N + col] = v;
                } else if (OUT_MODE == 1) {
                    ((unsigned short*)C)[(size_t)row * N + col] = f2b(v);
                } else {
                    ((unsigned short*)C)[((size_t)(col >> 5) * M + row) * HID
                                         + (col & 31)] = f2b(v);
                }
            }
        }
    }
}

// ------------- attention coefficients, layer 1 (head-major) -------------
__global__ void att1_kernel(const unsigned short* __restrict__ h1hm,
                            const float* __restrict__ att_src,
                            const float* __restrict__ att_dst,
                            float* __restrict__ a_src,
                            float* __restrict__ a_dst, int Nn) {
    const int n = blockIdx.x * blockDim.x + threadIdx.x;
    const int h = blockIdx.y;
    if (n >= Nn) return;
    const unsigned short* hp = h1hm + ((size_t)h * Nn + n) * HID;
    const float* as = att_src + h * HID;
    const float* ad = att_dst + h * HID;
    float s = 0.f, d = 0.f;
#pragma unroll
    for (int f = 0; f < HID; ++f) {
        const float v = b2f(hp[f]);
        s += v * as[f];
        d += v * ad[f];
    }
    a_src[(size_t)h * Nn + n] = s;
    a_dst[(size_t)h * Nn + n] = d;
}

__global__ void att2_kernel(const unsigned short* __restrict__ h2b,
                            const float* __restrict__ att_src,
                            const float* __restrict__ att_dst,
                            float* __restrict__ a_src,
                            float* __restrict__ a_dst, int Nn) {
    const int n = blockIdx.x * blockDim.x + threadIdx.x;
    if (n >= Nn) return;
    const unsigned short* hp = h2b + (size_t)n * F2;
    float s = 0.f, d = 0.f;
#pragma unroll
    for (int f = 0; f < F2; ++f) {
        const float v = b2f(hp[f]);
        s += v * att_src[f];
        d += v * att_dst[f];
    }
    a_src[n] = s;
    a_dst[n] = d;
}

// ------- layer-1 gather: head-split (XCD-pinned), edge-slot parallel -----
// head = blockIdx&7. Wave = 4 nodes (sub=lane>>4) x 4 edge slots
// (slot=(lane>>2)&3) x 4 channel lanes (cl=lane&3). Each round consumes
// 16 edges/node; slot partials reduced with shfl_xor(4,8) at the end.
__global__ __launch_bounds__(256) void gather1_kernel(
        const int* __restrict__ cursor, const int* __restrict__ bucket,
        const float* __restrict__ a_src, const float* __restrict__ a_dst,
        const unsigned short* __restrict__ h1hm, const float* __restrict__ b1,
        unsigned short* __restrict__ out1b, int Nn) {
    const int h = blockIdx.x & 7;
    const int lane = threadIdx.x & 63;
    const int wv = threadIdx.x >> 6;
    const int sub  = lane >> 4;          // node slot 0..3
    const int slot = (lane >> 2) & 3;    // edge slot 0..3
    const int cl   = lane & 3;           // channel group, c = cl*8
    int d = (blockIdx.x >> 3) * 16 + wv * 4 + sub;
    const bool dvalid = d < Nn;
    if (!dvalid) d = Nn - 1;             // no early return: shuffles below

    const unsigned short* hh = h1hm + (size_t)h * Nn * HID;
    const float* asrc = a_src + (size_t)h * Nn;
    const float adst = a_dst[(size_t)h * Nn + d];

    float denom = 0.f, acc[8] = {};
    if (slot == 0) {   // self-loop counted once
        const float w = __expf(leaky(asrc[d] + adst));
        const u16x8 v = *(const u16x8*)&hh[(size_t)d * HID + cl * 8];
        denom = w;
#pragma unroll
        for (int q = 0; q < 8; ++q) acc[q] = w * b2f(v[q]);
    }
    const int base = d * CAP;
    const int cnt = min(cursor[d], CAP);
    for (int i = slot * 4; i < cnt; i += 16) {
        const int4 s4 = *(const int4*)&bucket[base + i];
        int s[4];
        bool ok[4];
        s[0] = s4.x; s[1] = s4.y; s[2] = s4.z; s[3] = s4.w;
#pragma unroll
        for (int j = 0; j < 4; ++j) {
            ok[j] = (i + j) < cnt;
            s[j] = ok[j] ? s[j] : d;
        }
        float e[4];
#pragma unroll
        for (int j = 0; j < 4; ++j) e[j] = asrc[s[j]];
        u16x8 vv[4];
#pragma unroll
        for (int j = 0; j < 4; ++j)
            vv[j] = *(const u16x8*)&hh[(size_t)s[j] * HID + cl * 8];
#pragma unroll
        for (int j = 0; j < 4; ++j) {
            float w = __expf(leaky(e[j] + adst));
            w = ok[j] ? w : 0.f;
            denom += w;
#pragma unroll
            for (int q = 0; q < 8; ++q) acc[q] += w * b2f(vv[j][q]);
        }
    }
    // reduce edge-slot partials (lane bits 2-3)
#pragma unroll
    for (int q = 0; q < 8; ++q) {
        acc[q] += __shfl_xor(acc[q], 4, 64);
        acc[q] += __shfl_xor(acc[q], 8, 64);
    }
    denom += __shfl_xor(denom, 4, 64);
    denom += __shfl_xor(denom, 8, 64);

    if (slot == 0 && dvalid) {
        const float inv = 1.f / denom;
        const int c = h * HID + cl * 8;
        u16x8 o;
#pragma unroll
        for (int q = 0; q < 8; ++q)
            o[q] = f2b(fmaxf(acc[q] * inv + b1[c + q], 0.f));
        *(u16x8*)&out1b[(size_t)d * F1 + c] = o;
    }
}

// ------- layer-2 gather: 1 node/wave x 4 edge slots x 16 ch-lanes -------
// slot=lane>>4 consumes 4-edge chunks; reduce with shfl_xor(16,32).
__global__ __launch_bounds__(256) void gather2_kernel(
        const int* __restrict__ cursor, const int* __restrict__ bucket,
        const float* __restrict__ a_src, const float* __restrict__ a_dst,
        const unsigned short* __restrict__ h2b, const float* __restrict__ b2,
        float* __restrict__ out, int Nn) {
    const int lane = threadIdx.x & 63;
    const int slot = lane >> 4;          // edge slot 0..3
    const int l    = lane & 15;          // channel group, c = l*4
    int d = blockIdx.x * 4 + (threadIdx.x >> 6);
    const bool dvalid = d < Nn;
    if (!dvalid) d = Nn - 1;
    const int c = l * 4;

    const float adst = a_dst[d];
    float a0 = 0.f, a1 = 0.f, a2 = 0.f, a3 = 0.f, denom = 0.f;
    if (slot == 0) {   // self-loop counted once
        const float w = __expf(leaky(a_src[d] + adst));
        const ushort4 v = *(const ushort4*)&h2b[(size_t)d * F2 + c];
        denom = w;
        a0 = w * b2f(v.x); a1 = w * b2f(v.y);
        a2 = w * b2f(v.z); a3 = w * b2f(v.w);
    }
    const int base = d * CAP;
    const int cnt = min(cursor[d], CAP);
    for (int i = slot * 4; i < cnt; i += 16) {
        const int4 s4 = *(const int4*)&bucket[base + i];
        int s[4] = { s4.x, s4.y, s4.z, s4.w };
        float e[4];
        ushort4 vv[4];
#pragma unroll
        for (int jj = 0; jj < 4; ++jj) {
            const bool ok = (i + jj) < cnt;
            const int ss = ok ? s[jj] : d;
            s[jj] = ok ? 1 : -1;            // validity flag
            e[jj] = a_src[ss];
            vv[jj] = *(const ushort4*)&h2b[(size_t)ss * F2 + c];
        }
#pragma unroll
        for (int jj = 0; jj < 4; ++jj) {
            float w = __expf(leaky(e[jj] + adst));
            w = s[jj] < 0 ? 0.f : w;
            denom += w;
            a0 += w * b2f(vv[jj].x); a1 += w * b2f(vv[jj].y);
            a2 += w * b2f(vv[jj].z); a3 += w * b2f(vv[jj].w);
        }
    }
    // reduce edge-slot partials (lane bits 4-5)
    a0 += __shfl_xor(a0, 16, 64); a0 += __shfl_xor(a0, 32, 64);
    a1 += __shfl_xor(a1, 16, 64); a1 += __shfl_xor(a1, 32, 64);
    a2 += __shfl_xor(a2, 16, 64); a2 += __shfl_xor(a2, 32, 64);
    a3 += __shfl_xor(a3, 16, 64); a3 += __shfl_xor(a3, 32, 64);
    denom += __shfl_xor(denom, 16, 64);
    denom += __shfl_xor(denom, 32, 64);

    if (slot == 0 && dvalid) {
        const float inv = 1.f / denom;
        float4 o;
        o.x = a0 * inv + b2[c + 0];
        o.y = a1 * inv + b2[c + 1];
        o.z = a2 * inv + b2[c + 2];
        o.w = a3 * inv + b2[c + 3];
        *(float4*)&out[(size_t)d * F2 + c] = o;
    }
}

extern "C" void kernel_launch(void* const* d_in, const int* in_sizes, int n_in,
                              void* d_out, int out_size, void* d_ws, size_t ws_size,
                              hipStream_t stream) {
    const float* x        = (const float*)d_in[0];
    const int*   ei       = (const int*)d_in[1];     // [2, E]
    const float* W1       = (const float*)d_in[2];   // [256,256]
    const float* att_src1 = (const float*)d_in[3];   // [8,32]
    const float* att_dst1 = (const float*)d_in[4];
    const float* b1       = (const float*)d_in[5];   // [256]
    const float* W2       = (const float*)d_in[6];   // [256,64]
    const float* att_src2 = (const float*)d_in[7];   // [1,64]
    const float* att_dst2 = (const float*)d_in[8];
    const float* b2       = (const float*)d_in[9];   // [64]
    float* out = (float*)d_out;                      // [N,64]

    const int Nn = in_sizes[0] / F1;    // 50000
    const int E  = in_sizes[1] / 2;     // 800000

    // workspace layout — wide-aligned arrays first
    char* p = (char*)d_ws;
    unsigned short* h1hm  = (unsigned short*)p; p += (size_t)Nn * F1 * 2; // [8][Nn][32]
    unsigned short* out1b = (unsigned short*)p; p += (size_t)Nn * F1 * 2;
    unsigned short* W1T   = (unsigned short*)p; p += (size_t)F1 * F1 * 2;
    unsigned short* W2T   = (unsigned short*)p; p += (size_t)F2 * F1 * 2;
    unsigned short* h2b   = (unsigned short*)p; p += (size_t)Nn * F2 * 2;
    float* a_src1 = (float*)p; p += (size_t)Nn * HEADS * 4;    // [8][Nn]
    float* a_dst1 = (float*)p; p += (size_t)Nn * HEADS * 4;    // [8][Nn]
    float* a_src2 = (float*)p; p += (size_t)Nn * 4;
    float* a_dst2 = (float*)p; p += (size_t)Nn * 4;
    int* cursor  = (int*)p; p += (size_t)Nn * 4;
    int* bucket  = (int*)p; p += (size_t)Nn * CAP * 4;         // 25.6 MB

    // --- setup: weight casts + cursor zero ---
    {
        const int total = F1 * F1 + F1 * F2 + Nn;
        setup_kernel<<<(total + 255) / 256, 256, 0, stream>>>(
            W1, W2, W1T, W2T, cursor, Nn);
    }
    // --- bucket scatter (by dst) ---
    scatter_kernel<<<(E + 255) / 256, 256, 0, stream>>>(ei, E, cursor, bucket);

    // --- layer 1 ---
    {
        dim3 grid((Nn + 127) / 128, F1 / 128);
        mfma_gemm<128, true, 2><<<grid, 256, 0, stream>>>(
            x, W1T, h1hm, Nn, F1, F1);
    }
    {
        dim3 grid((Nn + 255) / 256, HEADS);
        att1_kernel<<<grid, 256, 0, stream>>>(
            h1hm, att_src1, att_dst1, a_src1, a_dst1, Nn);
    }
    gather1_kernel<<<((Nn + 15) / 16) * 8, 256, 0, stream>>>(
        cursor, bucket, a_src1, a_dst1, h1hm, b1, out1b, Nn);

    // --- layer 2 ---
    {
        dim3 grid((Nn + 127) / 128, F2 / 64);
        mfma_gemm<64, false, 1><<<grid, 256, 0, stream>>>(
            out1b, W2T, h2b, Nn, F2, F1);
    }
    att2_kernel<<<(Nn + 255) / 256, 256, 0, stream>>>(
        h2b, att_src2, att_dst2, a_src2, a_dst2, Nn);
    gather2_kernel<<<(Nn + 3) / 4, 256, 0, stream>>>(
        cursor, bucket, a_src2, a_dst2, h2b, b2, out, Nn);
}

// Round 3
// 290.911 us; speedup vs baseline: 1.0194x; 1.0073x over previous
//
#include <hip/hip_runtime.h>
#include <hip/hip_bf16.h>

// GAT 2-layer forward. N=50000, E=800000 (+N self loops), IN=256,
// layer1: 8 heads x 32 (concat -> 256), relu, layer2: 256 -> 64, 1 head.
// Round 13b (resubmit — round 13 hit an infra container failure):
// head-FUSED gather1 (node-major h1, wave = 2 nodes x 32 lanes, 512B
// coalesced row gathers, one bucket pass for all 8 heads) + sentinel
// bucket padding (pad to x4 with node Nn whose a_src=-1e30 -> w=0) which
// removes all tail masking. gather2 fused the same way (4 nodes x 16 lanes).

#define HEADS 8
#define HID 32
#define F1 256   // IN and layer-1 output width (8*32)
#define F2 64    // layer-2 output width
#define NEG_SLOPE 0.2f
#define CAP 128  // bucket slots per node (max in-degree ~45 for Poisson(16))

typedef __attribute__((ext_vector_type(8))) short bf16x8;
typedef __attribute__((ext_vector_type(4))) float f32x4;
typedef __attribute__((ext_vector_type(8))) unsigned short u16x8;

__device__ __forceinline__ unsigned short f2b(float f) {
    union { float f; unsigned int i; } x; x.f = f;
    unsigned int r = x.i + 0x7fffu + ((x.i >> 16) & 1u);  // RNE
    return (unsigned short)(r >> 16);
}
__device__ __forceinline__ float b2f(unsigned short u) {
    union { unsigned int i; float f; } x; x.i = ((unsigned int)u) << 16;
    return x.f;
}
__device__ __forceinline__ float leaky(float v) {
    return v > 0.f ? v : NEG_SLOPE * v;
}

// ------- setup: W1T, W2T casts + cursor zero + sentinel rows ------------
__global__ void setup_kernel(const float* __restrict__ W1,
                             const float* __restrict__ W2,
                             unsigned short* __restrict__ W1T,
                             unsigned short* __restrict__ W2T,
                             int* __restrict__ cursor,
                             unsigned short* __restrict__ h1b,
                             unsigned short* __restrict__ h2b,
                             float* __restrict__ a_src8,
                             float* __restrict__ a_src2, int Nn) {
    const int i = blockIdx.x * 256 + threadIdx.x;
    const int T1 = F1 * F1;
    const int T2 = T1 + F1 * F2;
    const int T3 = T2 + Nn;
    const int T4 = T3 + F1;
    const int T5 = T4 + F2;
    const int T6 = T5 + 8;
    const int T7 = T6 + 1;
    if (i < T1) {                            // W1 [F1,F1] -> W1T [n][k]
        const int k = i >> 8, n = i & (F1 - 1);
        W1T[(size_t)n * F1 + k] = f2b(W1[i]);
    } else if (i < T2) {                     // W2 [F1,F2] -> W2T [n][k]
        const int j = i - T1;
        const int k = j >> 6, n = j & (F2 - 1);
        W2T[(size_t)n * F1 + k] = f2b(W2[j]);
    } else if (i < T3) {
        cursor[i - T2] = 0;
    } else if (i < T4) {                     // h1b sentinel row = 0
        h1b[(size_t)Nn * F1 + (i - T3)] = 0;
    } else if (i < T5) {                     // h2b sentinel row = 0
        h2b[(size_t)Nn * F2 + (i - T4)] = 0;
    } else if (i < T6) {                     // a_src8 sentinel -> w = 0
        a_src8[(size_t)Nn * 8 + (i - T5)] = -1e30f;
    } else if (i < T7) {
        a_src2[Nn] = -1e30f;
    }
}

// ---------------- bucket scatter (by dst) -------------------------------
__global__ void scatter_kernel(const int* __restrict__ ei, int E,
                               int* __restrict__ cursor,
                               int* __restrict__ bucket) {
    const int e = blockIdx.x * blockDim.x + threadIdx.x;
    if (e >= E) return;
    const int d = ei[E + e];
    const int pos = atomicAdd(&cursor[d], 1);
    if (pos < CAP) bucket[(size_t)d * CAP + pos] = ei[e];
}

// -------- pad buckets to multiple of 4 with sentinel node Nn ------------
__global__ void pad_kernel(const int* __restrict__ cursor,
                           int* __restrict__ bucket, int Nn) {
    const int d = blockIdx.x * 256 + threadIdx.x;
    if (d >= Nn) return;
    const int c0 = min(cursor[d], CAP);
    const int ce = min((c0 + 3) & ~3, CAP);
    for (int i = c0; i < ce; ++i) bucket[(size_t)d * CAP + i] = Nn;
}

// ---------------- MFMA GEMM: C[M,N] = A[M,K] @ BT[N,K]^T ----------------
// OUT_MODE: 0 = fp32 node-major, 1 = bf16 node-major
template<int BN, bool A_FP32, int OUT_MODE>
__global__ __launch_bounds__(256) void mfma_gemm(
        const void* __restrict__ A,
        const unsigned short* __restrict__ BT,
        void* __restrict__ C, int M, int N, int K) {
    constexpr int BM = 128, BK = 32;
    __shared__ unsigned short As[BM * BK];
    __shared__ unsigned short Bs[BN * BK];
    const int tid = threadIdx.x;
    const int wave = tid >> 6, lane = tid & 63;
    const int quad = lane >> 4, l16 = lane & 15;
    const int brow = blockIdx.x * BM;
    const int bcol = blockIdx.y * BN;

    constexpr int MI = (BN == 128) ? 4 : 2;
    constexpr int NJ = 4;
    const int wm = (BN == 128) ? (wave & 1) * 64 : wave * 32;
    const int wn = (BN == 128) ? (wave >> 1) * 64 : 0;

    f32x4 acc[MI][NJ] = {};

    for (int k0 = 0; k0 < K; k0 += BK) {
#pragma unroll
        for (int it = 0; it < (BM * BK) / (256 * 8); ++it) {
            const int idx = it * 256 + tid;
            const int r = idx >> 2;
            const int kk = (idx & 3) * 8;
            const int gr = brow + r;
            if (A_FP32) {
                const float* Af = (const float*)A;
                float4 a0 = make_float4(0.f, 0.f, 0.f, 0.f);
                float4 a1 = make_float4(0.f, 0.f, 0.f, 0.f);
                if (gr < M) {
                    a0 = *(const float4*)&Af[(size_t)gr * K + k0 + kk];
                    a1 = *(const float4*)&Af[(size_t)gr * K + k0 + kk + 4];
                }
                ushort4 lo, hi;
                lo.x = f2b(a0.x); lo.y = f2b(a0.y); lo.z = f2b(a0.z); lo.w = f2b(a0.w);
                hi.x = f2b(a1.x); hi.y = f2b(a1.y); hi.z = f2b(a1.z); hi.w = f2b(a1.w);
                *(ushort4*)&As[r * BK + kk] = lo;
                *(ushort4*)&As[r * BK + kk + 4] = hi;
            } else {
                const unsigned short* Ab = (const unsigned short*)A;
                uint4 v = make_uint4(0u, 0u, 0u, 0u);
                if (gr < M) v = *(const uint4*)&Ab[(size_t)gr * K + k0 + kk];
                *(uint4*)&As[r * BK + kk] = v;
            }
        }
#pragma unroll
        for (int it = 0; it < (BN * BK) / (256 * 8); ++it) {
            const int idx = it * 256 + tid;
            const int r = idx >> 2;
            const int kk = (idx & 3) * 8;
            const uint4 v = *(const uint4*)&BT[(size_t)(bcol + r) * K + k0 + kk];
            *(uint4*)&Bs[r * BK + kk] = v;
        }
        __syncthreads();
        bf16x8 af[MI], bfr[NJ];
#pragma unroll
        for (int i = 0; i < MI; ++i)
            af[i] = *(const bf16x8*)&As[(wm + i * 16 + l16) * BK + quad * 8];
#pragma unroll
        for (int j = 0; j < NJ; ++j)
            bfr[j] = *(const bf16x8*)&Bs[(wn + j * 16 + l16) * BK + quad * 8];
#pragma unroll
        for (int i = 0; i < MI; ++i)
#pragma unroll
            for (int j = 0; j < NJ; ++j)
                acc[i][j] = __builtin_amdgcn_mfma_f32_16x16x32_bf16(
                    af[i], bfr[j], acc[i][j], 0, 0, 0);
        __syncthreads();
    }
#pragma unroll
    for (int i = 0; i < MI; ++i) {
#pragma unroll
        for (int r = 0; r < 4; ++r) {
            const int row = brow + wm + i * 16 + quad * 4 + r;
            if (row >= M) continue;
#pragma unroll
            for (int j = 0; j < NJ; ++j) {
                const int col = bcol + wn + j * 16 + l16;
                const float v = acc[i][j][r];
                if (OUT_MODE == 0) {
                    ((float*)C)[(size_t)row * N + col] = v;
                } else {
                    ((unsigned short*)C)[(size_t)row * N + col] = f2b(v);
                }
            }
        }
    }
}

// ------- attention coefficients, layer 1 (node-major, interleaved) ------
// thread = (n, h); reads 64B contiguous; writes a_src8/a_dst8 [Nn][8].
__global__ void att1n_kernel(const unsigned short* __restrict__ h1b,
                             const float* __restrict__ att_src,
                             const float* __restrict__ att_dst,
                             float* __restrict__ a_src8,
                             float* __restrict__ a_dst8, int Nn) {
    const int idx = blockIdx.x * 256 + threadIdx.x;
    const int n = idx >> 3, h = idx & 7;
    if (n >= Nn) return;
    const unsigned short* hp = h1b + (size_t)n * F1 + h * HID;
    const float* as = att_src + h * HID;
    const float* ad = att_dst + h * HID;
    float s = 0.f, dd = 0.f;
#pragma unroll
    for (int f = 0; f < HID; ++f) {
        const float v = b2f(hp[f]);
        s += v * as[f];
        dd += v * ad[f];
    }
    a_src8[(size_t)n * 8 + h] = s;
    a_dst8[(size_t)n * 8 + h] = dd;
}

__global__ void att2_kernel(const unsigned short* __restrict__ h2b,
                            const float* __restrict__ att_src,
                            const float* __restrict__ att_dst,
                            float* __restrict__ a_src,
                            float* __restrict__ a_dst, int Nn) {
    const int n = blockIdx.x * blockDim.x + threadIdx.x;
    if (n >= Nn) return;
    const unsigned short* hp = h2b + (size_t)n * F2;
    float s = 0.f, d = 0.f;
#pragma unroll
    for (int f = 0; f < F2; ++f) {
        const float v = b2f(hp[f]);
        s += v * att_src[f];
        d += v * att_dst[f];
    }
    a_src[n] = s;
    a_dst[n] = d;
}

// ---------------- layer-1 gather: all heads fused ------------------------
// Wave = 2 nodes x 32 lanes. Lane l owns channels [l*8, l*8+8) (head l>>2).
// Per round: 1 int4 bucket read + 4 edges; each edge = one 512B coalesced
// row gather. Sentinel-padded buckets: no tail masks. No cross-lane reduce.
__global__ __launch_bounds__(256) void gather1_kernel(
        const int* __restrict__ cursor, const int* __restrict__ bucket,
        const float* __restrict__ a_src8, const float* __restrict__ a_dst8,
        const unsigned short* __restrict__ h1b, const float* __restrict__ b1,
        unsigned short* __restrict__ out1b, int Nn) {
    const int lane = threadIdx.x & 63;
    const int wv   = threadIdx.x >> 6;
    const int slot = lane >> 5;          // node slot 0..1
    const int l    = lane & 31;          // channel lane: ch = l*8
    const int hd   = l >> 2;             // head 0..7
    const int d = blockIdx.x * 8 + wv * 2 + slot;
    if (d >= Nn) return;

    const float adst = a_dst8[(size_t)d * 8 + hd];

    float denom, acc[8];
    {   // self-loop
        const float w = __expf(leaky(a_src8[(size_t)d * 8 + hd] + adst));
        const u16x8 v = *(const u16x8*)&h1b[(size_t)d * F1 + l * 8];
        denom = w;
#pragma unroll
        for (int q = 0; q < 8; ++q) acc[q] = w * b2f(v[q]);
    }
    const int base = d * CAP;
    const int cnt = min(cursor[d], CAP);
    const int cntp = (cnt + 3) & ~3;     // sentinel-padded length
    for (int i = 0; i < cntp; i += 4) {
        const int4 s4 = *(const int4*)&bucket[base + i];
        int s[4] = { s4.x, s4.y, s4.z, s4.w };
        float e[4];
#pragma unroll
        for (int j = 0; j < 4; ++j) e[j] = a_src8[(size_t)s[j] * 8 + hd];
        u16x8 vv[4];
#pragma unroll
        for (int j = 0; j < 4; ++j)
            vv[j] = *(const u16x8*)&h1b[(size_t)s[j] * F1 + l * 8];
#pragma unroll
        for (int j = 0; j < 4; ++j) {
            const float w = __expf(leaky(e[j] + adst));
            denom += w;
#pragma unroll
            for (int q = 0; q < 8; ++q) acc[q] += w * b2f(vv[j][q]);
        }
    }
    const float inv = 1.f / denom;
    const int c = l * 8;
    const float4 bv0 = *(const float4*)&b1[c];
    const float4 bv1 = *(const float4*)&b1[c + 4];
    u16x8 o;
    o[0] = f2b(fmaxf(acc[0] * inv + bv0.x, 0.f));
    o[1] = f2b(fmaxf(acc[1] * inv + bv0.y, 0.f));
    o[2] = f2b(fmaxf(acc[2] * inv + bv0.z, 0.f));
    o[3] = f2b(fmaxf(acc[3] * inv + bv0.w, 0.f));
    o[4] = f2b(fmaxf(acc[4] * inv + bv1.x, 0.f));
    o[5] = f2b(fmaxf(acc[5] * inv + bv1.y, 0.f));
    o[6] = f2b(fmaxf(acc[6] * inv + bv1.z, 0.f));
    o[7] = f2b(fmaxf(acc[7] * inv + bv1.w, 0.f));
    *(u16x8*)&out1b[(size_t)d * F1 + c] = o;
}

// ---------------- layer-2 gather: 4 nodes/wave x 16 lanes ----------------
// Lane l owns channels [l*4, l*4+4). Sentinel-padded buckets, no masks.
__global__ __launch_bounds__(256) void gather2_kernel(
        const int* __restrict__ cursor, const int* __restrict__ bucket,
        const float* __restrict__ a_src, const float* __restrict__ a_dst,
        const unsigned short* __restrict__ h2b, const float* __restrict__ b2,
        float* __restrict__ out, int Nn) {
    const int lane = threadIdx.x & 63;
    const int slot = lane >> 4;          // node slot 0..3
    const int l    = lane & 15;          // channel lane: ch = l*4
    const int d = blockIdx.x * 16 + (threadIdx.x >> 6) * 4 + slot;
    if (d >= Nn) return;
    const int c = l * 4;

    const float adst = a_dst[d];
    float a0, a1, a2, a3, denom;
    {   // self-loop
        const float w = __expf(leaky(a_src[d] + adst));
        const ushort4 v = *(const ushort4*)&h2b[(size_t)d * F2 + c];
        denom = w;
        a0 = w * b2f(v.x); a1 = w * b2f(v.y);
        a2 = w * b2f(v.z); a3 = w * b2f(v.w);
    }
    const int base = d * CAP;
    const int cnt = min(cursor[d], CAP);
    const int cntp = (cnt + 3) & ~3;
    for (int i = 0; i < cntp; i += 4) {
        const int4 s4 = *(const int4*)&bucket[base + i];
        int s[4] = { s4.x, s4.y, s4.z, s4.w };
        float e[4];
        ushort4 vv[4];
#pragma unroll
        for (int jj = 0; jj < 4; ++jj) {
            e[jj] = a_src[s[jj]];
            vv[jj] = *(const ushort4*)&h2b[(size_t)s[jj] * F2 + c];
        }
#pragma unroll
        for (int jj = 0; jj < 4; ++jj) {
            const float w = __expf(leaky(e[jj] + adst));
            denom += w;
            a0 += w * b2f(vv[jj].x); a1 += w * b2f(vv[jj].y);
            a2 += w * b2f(vv[jj].z); a3 += w * b2f(vv[jj].w);
        }
    }
    const float inv = 1.f / denom;
    float4 o;
    o.x = a0 * inv + b2[c + 0];
    o.y = a1 * inv + b2[c + 1];
    o.z = a2 * inv + b2[c + 2];
    o.w = a3 * inv + b2[c + 3];
    *(float4*)&out[(size_t)d * F2 + c] = o;
}

extern "C" void kernel_launch(void* const* d_in, const int* in_sizes, int n_in,
                              void* d_out, int out_size, void* d_ws, size_t ws_size,
                              hipStream_t stream) {
    const float* x        = (const float*)d_in[0];
    const int*   ei       = (const int*)d_in[1];     // [2, E]
    const float* W1       = (const float*)d_in[2];   // [256,256]
    const float* att_src1 = (const float*)d_in[3];   // [8,32]
    const float* att_dst1 = (const float*)d_in[4];
    const float* b1       = (const float*)d_in[5];   // [256]
    const float* W2       = (const float*)d_in[6];   // [256,64]
    const float* att_src2 = (const float*)d_in[7];   // [1,64]
    const float* att_dst2 = (const float*)d_in[8];
    const float* b2       = (const float*)d_in[9];   // [64]
    float* out = (float*)d_out;                      // [N,64]

    const int Nn = in_sizes[0] / F1;    // 50000
    const int E  = in_sizes[1] / 2;     // 800000

    // workspace layout — wide-aligned arrays first (all chunks 16B-multiple)
    char* p = (char*)d_ws;
    unsigned short* h1b   = (unsigned short*)p; p += (size_t)(Nn + 1) * F1 * 2;
    unsigned short* out1b = (unsigned short*)p; p += (size_t)Nn * F1 * 2;
    unsigned short* W1T   = (unsigned short*)p; p += (size_t)F1 * F1 * 2;
    unsigned short* W2T   = (unsigned short*)p; p += (size_t)F2 * F1 * 2;
    unsigned short* h2b   = (unsigned short*)p; p += (size_t)(Nn + 1) * F2 * 2;
    float* a_src8 = (float*)p; p += (size_t)(Nn + 1) * 8 * 4;  // [Nn+1][8]
    float* a_dst8 = (float*)p; p += (size_t)Nn * 8 * 4;        // [Nn][8]
    float* a_src2 = (float*)p; p += (size_t)(Nn + 4) * 4;      // padded to 16B
    float* a_dst2 = (float*)p; p += (size_t)Nn * 4;
    int* cursor  = (int*)p; p += (size_t)Nn * 4;
    int* bucket  = (int*)p; p += (size_t)Nn * CAP * 4;         // 25.6 MB

    // --- setup: weight casts + cursor zero + sentinel rows ---
    {
        const int total = F1 * F1 + F1 * F2 + Nn + F1 + F2 + 8 + 1;
        setup_kernel<<<(total + 255) / 256, 256, 0, stream>>>(
            W1, W2, W1T, W2T, cursor, h1b, h2b, a_src8, a_src2, Nn);
    }
    // --- bucket scatter (by dst) + sentinel pad ---
    scatter_kernel<<<(E + 255) / 256, 256, 0, stream>>>(ei, E, cursor, bucket);
    pad_kernel<<<(Nn + 255) / 256, 256, 0, stream>>>(cursor, bucket, Nn);

    // --- layer 1 ---
    {
        dim3 grid((Nn + 127) / 128, F1 / 128);
        mfma_gemm<128, true, 1><<<grid, 256, 0, stream>>>(
            x, W1T, h1b, Nn, F1, F1);
    }
    att1n_kernel<<<(Nn * 8 + 255) / 256, 256, 0, stream>>>(
        h1b, att_src1, att_dst1, a_src8, a_dst8, Nn);
    gather1_kernel<<<(Nn + 7) / 8, 256, 0, stream>>>(
        cursor, bucket, a_src8, a_dst8, h1b, b1, out1b, Nn);

    // --- layer 2 ---
    {
        dim3 grid((Nn + 127) / 128, F2 / 64);
        mfma_gemm<64, false, 1><<<grid, 256, 0, stream>>>(
            out1b, W2T, h2b, Nn, F2, F1);
    }
    att2_kernel<<<(Nn + 255) / 256, 256, 0, stream>>>(
        h2b, att_src2, att_dst2, a_src2, a_dst2, Nn);
    gather2_kernel<<<(Nn + 15) / 16, 256, 0, stream>>>(
        cursor, bucket, a_src2, a_dst2, h2b, b2, out, Nn);
}